// Round 2
// baseline (71.279 us; speedup 1.0000x reference)
//
#include <hip/hip_runtime.h>

// out[o,k,h,m] = sum_{i,j} p[o,i,(h-1)%14, m+j] * w[i,k,j]
// p[q]=0 for q in {0,15}; p[q] = x[o,i,n,(q-2)%14] for q in [1,14], n=(h-1)%14
//
// Grid: (kt=8, h=14, o=2) = 224 blocks. Block: 896 threads = 2 K-halves x
// (32 kk x 14 m). Split-K: half 0 reduces i in [0,128), half 1 reduces
// [128,256); half-1 partials go through LDS, half 0 adds + stores.
// 224 x 14 = 3136 waves ~ 3 waves/SIMD (vs 1.5 in R1), per-thread chain halved.

#define BT 896

__global__ __launch_bounds__(BT) void shiftconv_kernel(
    const float* __restrict__ x,   // (2,256,14,14) flat
    const float* __restrict__ w,   // (256,256,3) flat
    float* __restrict__ out)       // (2,256,14,14) flat
{
    __shared__ float xs[256 * 16];   // 16 KB padded p rows
    __shared__ float part[448];      // split-K partials

    const int kt = blockIdx.x;       // 0..7
    const int h  = blockIdx.y;       // 0..13
    const int o  = blockIdx.z;       // 0..1
    const int t  = threadIdx.x;      // 0..895
    const int n  = (h + 13) % 14;

    // ---- stage x[o, :, n, :] into padded LDS rows ----
    for (int e = t; e < 512; e += BT) {
        xs[(e >> 1) * 16 + (e & 1) * 15] = 0.0f;
    }
    for (int e = t; e < 256 * 14; e += BT) {
        int i  = e / 14;
        int ww = e - i * 14;
        float v = x[((size_t)(o * 256 + i) * 14 + n) * 14 + ww];
        int q = (ww <= 12) ? (ww + 2) : 1;
        xs[i * 16 + q] = v;
    }
    __syncthreads();

    const int half = (t >= 448) ? 1 : 0;     // wave-uniform (waves 0-6 vs 7-13)
    const int s    = t - 448 * half;
    const int kk   = s & 31;
    const int m    = s >> 5;                 // 0..13
    const int kglob = kt * 32 + kk;
    const int i0   = half * 128;

    const float* wp = w + ((size_t)i0 * 256 + kglob) * 3;  // stride 768 per i
    const float* xp = xs + i0 * 16 + m;

    float acc0 = 0.0f, acc1 = 0.0f;
#pragma unroll 8
    for (int i = 0; i < 128; i += 2) {
        acc0 = fmaf(xp[0],  wp[0],   acc0);
        acc0 = fmaf(xp[1],  wp[1],   acc0);
        acc0 = fmaf(xp[2],  wp[2],   acc0);
        acc1 = fmaf(xp[16], wp[768], acc1);
        acc1 = fmaf(xp[17], wp[769], acc1);
        acc1 = fmaf(xp[18], wp[770], acc1);
        wp += 1536;
        xp += 32;
    }
    float acc = acc0 + acc1;

    if (half) part[s] = acc;
    __syncthreads();
    if (!half) {
        acc += part[s];
        out[((size_t)(o * 256 + kglob) * 14 + h) * 14 + m] = acc;
    }
}

extern "C" void kernel_launch(void* const* d_in, const int* in_sizes, int n_in,
                              void* d_out, int out_size, void* d_ws, size_t ws_size,
                              hipStream_t stream) {
    const float* x = (const float*)d_in[0];   // (1,512,14,14) = (2,256,14,14)
    const float* w = (const float*)d_in[1];   // (256,256,3)
    float* out = (float*)d_out;               // (1,512,14,14)

    dim3 grid(8, 14, 2);
    dim3 block(BT);
    shiftconv_kernel<<<grid, block, 0, stream>>>(x, w, out);
}

// Round 3
// 63.349 us; speedup vs baseline: 1.1252x; 1.1252x over previous
//
#include <hip/hip_runtime.h>

// out[o,k,h,m] = sum_{i,j} p[o,i,(h-1)%14, m+j] * w[i,k,j]
// p[q]=0 for q in {0,15}; p[q] = x[o,i,n,(q-2)%14] for q in [1,14], n=(h-1)%14
//
// Grid (8,14,2)=224 blocks, block 896 = mp(0..6) x s(0..3) x kk(0..31).
// Split-K x4: thread reduces i in [64s, 64s+64), computes outputs m=2mp,2mp+1.
// w loaded as float3 (12B contiguous/lane), xs as 2x float2. Partials of
// s=1..3 reduced through LDS by s=0.

#define BT 896

__global__ __launch_bounds__(BT) void shiftconv_kernel(
    const float* __restrict__ x,   // (2,256,14,14)
    const float* __restrict__ w,   // (256,256,3)
    float* __restrict__ out)       // (2,256,14,14)
{
    __shared__ float xs[256 * 16];     // padded p rows, 16 KB
    __shared__ float part[3 * 7 * 64]; // split-K partials (s-1, mp, kk*2+u)

    const int kt = blockIdx.x;   // 0..7
    const int h  = blockIdx.y;   // 0..13
    const int o  = blockIdx.z;   // 0..1
    const int t  = threadIdx.x;  // 0..895
    const int n  = (h + 13) % 14;

    // ---- stage x[o,:,n,:] into padded LDS rows ----
    for (int e = t; e < 512; e += BT)
        xs[(e >> 1) * 16 + (e & 1) * 15] = 0.0f;
    for (int e = t; e < 256 * 14; e += BT) {
        int i  = e / 14;
        int ww = e - i * 14;
        float v = x[((size_t)(o * 256 + i) * 14 + n) * 14 + ww];
        xs[i * 16 + ((ww <= 12) ? (ww + 2) : 1)] = v;
    }
    __syncthreads();

    const int kk = t & 31;
    const int s  = (t >> 5) & 3;   // split-K index
    const int mp = t >> 7;         // 0..6 -> m pair
    const int kglob = kt * 32 + kk;
    const int m0 = 2 * mp;

    const float* wp = w + ((size_t)(s * 64) * 256 + kglob) * 3; // stride 768/i
    const float* xp = xs + (s * 64) * 16 + m0;

    float a0 = 0.f, a1 = 0.f, b0 = 0.f, b1 = 0.f;
#pragma unroll 4
    for (int i = 0; i < 64; ++i) {
        float3 wv  = *reinterpret_cast<const float3*>(wp);
        float2 t01 = *reinterpret_cast<const float2*>(xp);
        float2 t23 = *reinterpret_cast<const float2*>(xp + 2);
        // m0 taps: t01.x t01.y t23.x ; m1 taps: t01.y t23.x t23.y
        a0 = fmaf(t01.x, wv.x, a0);
        a1 = fmaf(t01.y, wv.y, a1);
        a0 = fmaf(t23.x, wv.z, a0);
        b0 = fmaf(t01.y, wv.x, b0);
        b1 = fmaf(t23.x, wv.y, b1);
        b0 = fmaf(t23.y, wv.z, b0);
        wp += 768;
        xp += 16;
    }
    float am = a0 + a1, bm = b0 + b1;

    if (s) {
        int base = ((s - 1) * 7 + mp) * 64 + kk * 2;
        part[base]     = am;
        part[base + 1] = bm;
    }
    __syncthreads();
    if (s == 0) {
        int base = mp * 64 + kk * 2;
        am += part[base]     + part[448 + base]     + part[896 + base];
        bm += part[base + 1] + part[448 + base + 1] + part[896 + base + 1];
        size_t off = ((size_t)(o * 256 + kglob) * 14 + h) * 14 + m0;
        out[off]     = am;
        out[off + 1] = bm;
    }
}

extern "C" void kernel_launch(void* const* d_in, const int* in_sizes, int n_in,
                              void* d_out, int out_size, void* d_ws, size_t ws_size,
                              hipStream_t stream) {
    const float* x = (const float*)d_in[0];
    const float* w = (const float*)d_in[1];
    float* out = (float*)d_out;

    dim3 grid(8, 14, 2);
    dim3 block(BT);
    shiftconv_kernel<<<grid, block, 0, stream>>>(x, w, out);
}

// Round 4
// 60.065 us; speedup vs baseline: 1.1867x; 1.0547x over previous
//
#include <hip/hip_runtime.h>

// out[o,k,h,m] = sum_{i,j} p[o,i,(h-1)%14, m+j] * w[i,k,j]
// p[q]=0 for q in {0,15}; p[q]=x[o,i,n,(q-2)%14], n=(h-1)%14
//
// Grid (8,14,2)=224 blocks, block 512 = kk2(0..15) x s(0..31).
// Each thread: i in [8s,8s+8), k in {kt*32+2kk2, +1}, ALL 14 m.
// Per i: 4 aligned ds_read_b128 (16-float xs row) + 2 float3 w loads + 84 FMA
//   -> LDS wave-ops per CU cut ~7x vs R3 (the measured bottleneck).
// Split-K partials: part[(s*28+mu)*17+kk2] (x17 pad kills bank conflicts),
// aliased over xs (sync separates uses). Reduction: 448 threads, 32 reads each.

#define BT 512

__global__ __launch_bounds__(BT) void shiftconv_kernel(
    const float* __restrict__ x,   // (2,256,14,14)
    const float* __restrict__ w,   // (256,256,3)
    float* __restrict__ out)       // (2,256,14,14)
{
    __shared__ __align__(16) float smem[32 * 28 * 17 + 2];  // 60936 B
    float* xs   = smem;        // phase 1: 256 padded rows x 16 floats
    float* part = smem;        // phase 2: split-K partials (aliased)

    const int kt = blockIdx.x;   // 0..7
    const int h  = blockIdx.y;   // 0..13
    const int o  = blockIdx.z;   // 0..1
    const int t  = threadIdx.x;  // 0..511
    const int n  = (h + 13) % 14;

    // ---- stage x[o,:,n,:] into padded LDS rows ----
    xs[(t >> 1) * 16 + (t & 1) * 15] = 0.0f;   // zeros at q=0,15 (512 slots)
    for (int e = t; e < 256 * 14; e += BT) {
        int i  = e / 14;
        int ww = e - i * 14;
        float v = x[((size_t)(o * 256 + i) * 14 + n) * 14 + ww];
        xs[i * 16 + ((ww <= 12) ? (ww + 2) : 1)] = v;
    }
    __syncthreads();

    const int kk2 = t & 15;      // k-pair index
    const int s   = t >> 4;      // 0..31 split-K
    const int kg0 = kt * 32 + 2 * kk2;
    const int i0  = s * 8;

    const float* wp = w + ((size_t)i0 * 256 + kg0) * 3;  // 6 contig floats/i
    const float* xp = xs + i0 * 16;

    float accA[14], accB[14];
#pragma unroll
    for (int m = 0; m < 14; ++m) { accA[m] = 0.f; accB[m] = 0.f; }

#pragma unroll
    for (int i = 0; i < 8; ++i) {
        float4 q0 = *reinterpret_cast<const float4*>(xp);
        float4 q1 = *reinterpret_cast<const float4*>(xp + 4);
        float4 q2 = *reinterpret_cast<const float4*>(xp + 8);
        float4 q3 = *reinterpret_cast<const float4*>(xp + 12);
        float r[16] = {q0.x,q0.y,q0.z,q0.w, q1.x,q1.y,q1.z,q1.w,
                       q2.x,q2.y,q2.z,q2.w, q3.x,q3.y,q3.z,q3.w};
        float3 wa = *reinterpret_cast<const float3*>(wp);
        float3 wb = *reinterpret_cast<const float3*>(wp + 3);
#pragma unroll
        for (int m = 0; m < 14; ++m) {
            accA[m] = fmaf(r[m],   wa.x, accA[m]);
            accA[m] = fmaf(r[m+1], wa.y, accA[m]);
            accA[m] = fmaf(r[m+2], wa.z, accA[m]);
            accB[m] = fmaf(r[m],   wb.x, accB[m]);
            accB[m] = fmaf(r[m+1], wb.y, accB[m]);
            accB[m] = fmaf(r[m+2], wb.z, accB[m]);
        }
        xp += 16;
        wp += 768;
    }

    __syncthreads();   // all xs reads done before part overwrites it

    // ---- write split-K partials: mu = u*14 + m ----
#pragma unroll
    for (int m = 0; m < 14; ++m) {
        part[(s * 28 + m)      * 17 + kk2] = accA[m];
        part[(s * 28 + 14 + m) * 17 + kk2] = accB[m];
    }
    __syncthreads();

    // ---- reduce over s, store ----
    if (t < 448) {
        int kk = t & 31;         // 0..31
        int m  = t >> 5;         // 0..13
        int k2 = kk >> 1;
        int mu = (kk & 1) * 14 + m;
        float sum = 0.f;
#pragma unroll
        for (int si = 0; si < 32; ++si)
            sum += part[(si * 28 + mu) * 17 + k2];
        out[((size_t)(o * 256 + kt * 32 + kk) * 14 + h) * 14 + m] = sum;
    }
}

extern "C" void kernel_launch(void* const* d_in, const int* in_sizes, int n_in,
                              void* d_out, int out_size, void* d_ws, size_t ws_size,
                              hipStream_t stream) {
    const float* x = (const float*)d_in[0];
    const float* w = (const float*)d_in[1];
    float* out = (float*)d_out;

    dim3 grid(8, 14, 2);
    dim3 block(BT);
    shiftconv_kernel<<<grid, block, 0, stream>>>(x, w, out);
}